// Round 14
// baseline (114.323 us; speedup 1.0000x reference)
//
#include <hip/hip_runtime.h>
#include <hip/hip_fp16.h>

#define NF 40
#define NE 128
#define NA 128
#define NW 144        // extended W rows: 128 W + 1 pw + 15 zero
#define NP 780        // NF*(NF-1)/2
#define NPT 784       // padded to 49*16
#define NMT 49        // m-tiles of 16 pairs
#define XS16_LD 136   // f16 x LDS row stride (ushorts): 272B rows, 16B aligned

typedef _Float16 half8 __attribute__((ext_vector_type(8)));
typedef float floatx4 __attribute__((ext_vector_type(4)));

// sum across each 16-lane row via DPP row_ror (VALU pipe, no DS traffic)
__device__ __forceinline__ float rowsum16(float x) {
    x += __int_as_float(__builtin_amdgcn_update_dpp(0, __float_as_int(x), 0x121, 0xf, 0xf, true)); // ror:1
    x += __int_as_float(__builtin_amdgcn_update_dpp(0, __float_as_int(x), 0x122, 0xf, 0xf, true)); // ror:2
    x += __int_as_float(__builtin_amdgcn_update_dpp(0, __float_as_int(x), 0x124, 0xf, 0xf, true)); // ror:4
    x += __int_as_float(__builtin_amdgcn_update_dpp(0, __float_as_int(x), 0x128, 0xf, 0xf, true)); // ror:8
    return x;
}

// ---- prep: [W; pw; 0] fp32 -> f16 (RNE) extended matrix ----
__global__ __launch_bounds__(256)
void afm_prep_kernel(const float* __restrict__ wg,
                     const float* __restrict__ pwg,
                     unsigned short* __restrict__ wbf)   // [NW][NE] f16
{
    const int t = blockIdx.x * 256 + threadIdx.x;   // 18*256 = 4608 threads
    if (t < NW * NE / 4) {
        const int row = t >> 5;
        const int c   = (t & 31) * 4;
        float4 v = make_float4(0.f, 0.f, 0.f, 0.f);
        if (row < NA)       v = *(const float4*)(wg + row * NE + c);
        else if (row == NA) v = *(const float4*)(pwg + c);
        union { _Float16 h[4]; ushort4 u; } cv;
        cv.h[0] = (_Float16)v.x;
        cv.h[1] = (_Float16)v.y;
        cv.h[2] = (_Float16)v.z;
        cv.h[3] = (_Float16)v.w;
        *(ushort4*)(wbf + t * 4) = cv.u;
    }
}

// out[b] = (sum_p e_p * Q_p) / (sum_p e_p) + pb, Q_p = hp_p . pw (9th MFMA tile)
__global__ __launch_bounds__(256, 2)
void afm_fused_kernel(const float* __restrict__ xg,          // [B, F, E]
                      const unsigned short* __restrict__ wbf,// [NW, E] f16 (prepped)
                      const float* __restrict__ wbg,         // [A]
                      const float* __restrict__ hg,          // [1, A]
                      const float* __restrict__ pbg,         // [1]
                      float* __restrict__ out)               // [B]
{
    __shared__ unsigned short xs16[NF][XS16_LD];  // 10880 B f16 x
    __shared__ float2 scq[NPT];                   // 6272 B (score, Q) per pair
    __shared__ float red_n[4], red_d[4];

    const int tid  = threadIdx.x;
    const int b    = blockIdx.x;
    const int lane = tid & 63;
    const int wid  = tid >> 6;
    const int col  = lane & 15;
    const int quad = (lane >> 4) & 3;

    // ---- stage x[b] as f16 ----
    const float* xb = xg + (size_t)b * (NF * NE);
    for (int t = tid; t < NF * (NE / 4); t += 256) {
        int row = t >> 5, c = (t & 31) * 4;
        float4 v = *(const float4*)(xb + row * NE + c);
        union { _Float16 h[4]; unsigned long long ull; } cv;
        cv.h[0] = (_Float16)v.x;
        cv.h[1] = (_Float16)v.y;
        cv.h[2] = (_Float16)v.z;
        cv.h[3] = (_Float16)v.w;
        *(unsigned long long*)&xs16[row][c] = cv.ull;   // 8B store, 8B aligned
    }
    // ---- per-lane epilogue constants ----
    float wbr[8], hr[8];
#pragma unroll
    for (int n = 0; n < 8; ++n) {
        wbr[n] = wbg[n * 16 + col];
        hr[n]  = hg[n * 16 + col];
    }
    // ---- extended-W B-fragments into registers (n=8 is the pw tile) ----
    half8 bfrag[9][4];
#pragma unroll
    for (int n = 0; n < 9; ++n)
#pragma unroll
        for (int k = 0; k < 4; ++k)
            bfrag[n][k] = *(const half8*)(const void*)(wbf + (n * 16 + col) * NE + k * 32 + quad * 8);
    __syncthreads();

    // ---- main MFMA loop: write (score, Q) pairs; exp deferred to post-pass ----
    for (int mt = wid; mt < NMT; mt += 4) {
        const int p0 = mt * 16;
        // arithmetic pair decode (no LDS read at chain head); clamp pad lanes
        int p = p0 + col;
        if (p > NP - 1) p = NP - 1;
        float sq = sqrtf((float)(6241 - 8 * p));
        int i  = (int)((79.0f - sq) * 0.5f);
        int rsb = (i * (79 - i)) >> 1;
        int rsn = ((i + 1) * (78 - i)) >> 1;
        if (rsn <= p) { i += 1; rsb = rsn; }                  // upward fixup
        if (rsb > p)  { i -= 1; rsb = (i * (79 - i)) >> 1; }  // downward fixup
        const int j = i + 1 + (p - rsb);
        const unsigned short* xi16 = &xs16[i][0];
        const unsigned short* xj16 = &xs16[j][0];

        floatx4 acc[9];
#pragma unroll
        for (int n = 0; n < 8; ++n)
            acc[n] = (floatx4){wbr[n], wbr[n], wbr[n], wbr[n]};  // bias folded into C-init
        acc[8] = (floatx4){0.f, 0.f, 0.f, 0.f};                  // Q accumulator

        __builtin_amdgcn_s_setprio(1);
#pragma unroll
        for (int k = 0; k < 4; ++k) {
            const int koff = k * 32 + quad * 8;
            half8 ih = *(const half8*)(const void*)(xi16 + koff);
            half8 jh = *(const half8*)(const void*)(xj16 + koff);
            half8 af = ih * jh;
#pragma unroll
            for (int n = 0; n < 9; ++n)
                acc[n] = __builtin_amdgcn_mfma_f32_16x16x32_f16(af, bfrag[n][k], acc[n], 0, 0, 0);
        }
        __builtin_amdgcn_s_setprio(0);

        // score[p] = sum_a relu(S[p,a]) * h[a]
        float ps[4] = {0.f, 0.f, 0.f, 0.f};
#pragma unroll
        for (int n = 0; n < 8; ++n) {
#pragma unroll
            for (int r = 0; r < 4; ++r)
                ps[r] += fmaxf(acc[n][r], 0.f) * hr[n];
        }
#pragma unroll
        for (int r = 0; r < 4; ++r) ps[r] = rowsum16(ps[r]);

        if (col == 0) {
#pragma unroll
            for (int r = 0; r < 4; ++r) {
                const int pp = p0 + quad * 4 + r;     // < NPT always
                scq[pp] = make_float2(ps[r], acc[8][r]);
            }
        }
    }
    __syncthreads();

    // ---- post-pass: exp + N/D accumulate (unshifted exp: scores ~ N(0,~1)) ----
    float nloc = 0.f, dloc = 0.f;
    for (int p = tid; p < NP; p += 256) {
        float2 v = scq[p];
        float e = __expf(v.x);
        nloc += e * v.y;
        dloc += e;
    }
#pragma unroll
    for (int off = 1; off < 64; off <<= 1) {
        nloc += __shfl_xor(nloc, off);
        dloc += __shfl_xor(dloc, off);
    }
    if (lane == 0) { red_n[wid] = nloc; red_d[wid] = dloc; }
    __syncthreads();
    if (tid == 0) {
        float N = red_n[0] + red_n[1] + red_n[2] + red_n[3];
        float D = red_d[0] + red_d[1] + red_d[2] + red_d[3];
        out[b] = N / D + pbg[0];
    }
}

extern "C" void kernel_launch(void* const* d_in, const int* in_sizes, int n_in,
                              void* d_out, int out_size, void* d_ws, size_t ws_size,
                              hipStream_t stream) {
    const float* xg  = (const float*)d_in[0];  // x [B,F,E]
    const float* wg  = (const float*)d_in[1];  // attn_w_w [A,E]
    const float* wbg = (const float*)d_in[2];  // attn_w_b [A]
    const float* hg  = (const float*)d_in[3];  // attn_h_w [1,A]
    // d_in[4] = attn_h_b : constant shift, cancels in softmax
    const float* pwg = (const float*)d_in[5];  // attn_p_w [1,E]
    const float* pbg = (const float*)d_in[6];  // attn_p_b [1]
    const int B = in_sizes[0] / (NF * NE);

    unsigned short* wbf = (unsigned short*)d_ws;   // 36864 B ([144][128] f16)

    afm_prep_kernel<<<18, 256, 0, stream>>>(wg, pwg, wbf);
    afm_fused_kernel<<<B, 256, 0, stream>>>(xg, wbf, wbg, hg, pbg, (float*)d_out);
}